// Round 14
// baseline (291.018 us; speedup 1.0000x reference)
//
#include <hip/hip_runtime.h>
#include <hip/hip_cooperative_groups.h>
#include <stdint.h>

namespace cg = cooperative_groups;

// PerfeCT membership: out[i] = +5.0 if (h,r,t) appears in data, else -5.0.
// key32 = ((h*15000+r)*15000+t) mod 2^32 (replicates reference's int32 overflow).
// r12 post-mortem: coop launch was REJECTED (absmax 5.0 = all-zero output = kernel
// never ran; return code ignored). r13: occupancy-gated coop grid (512 if 2 blk/CU
// co-residency confirmed, else 256) + return-code check + byte-identical r11
// 4-kernel fallback. Stateless decision -> identical work every call.

typedef int iv4 __attribute__((ext_vector_type(4)));

#define EMPTY  0xFFFFFFFFu
#define BWORDS 16384     // 2^19-bit bloom = 64 KB LDS
#define TPB    1024

static __device__ __forceinline__ uint32_t mix32(uint32_t x) {
    x ^= x >> 16; x *= 0x85ebca6bu;
    x ^= x >> 13; x *= 0xc2b2ae35u;
    x ^= x >> 16;
    return x;
}
static __device__ __forceinline__ uint32_t hash2(uint32_t x) {
    return mix32(x ^ 0x9E3779B9u);
}
static __device__ __forceinline__ uint32_t key32(int h, int r, int t) {
    return ((uint32_t)h * 15000u + (uint32_t)r) * 15000u + (uint32_t)t;
}
static __device__ __forceinline__ void bloom_wm(uint32_t key, uint32_t* w, uint32_t* m) {
    uint32_t z = mix32(key);
    *w = z & (BWORDS - 1u);
    *m = (1u << ((z >> 14) & 31u)) | (1u << ((z >> 19) & 31u));
}

static __device__ __forceinline__ void probe_mark(uint32_t key,
                                                  const uint32_t* __restrict__ keys,
                                                  uint32_t* __restrict__ flagbits,
                                                  uint32_t tmask) {
    uint32_t slot = hash2(key) & tmask;
    while (true) {
        uint32_t v = keys[slot];
        if (v == key) { atomicOr(&flagbits[slot >> 5], 1u << (slot & 31)); return; }
        if (v == EMPTY) return;
        slot = (slot + 1) & tmask;
    }
}

// ================= Fused cooperative kernel =================
__global__ __launch_bounds__(TPB, 8) void k_fused(
        const int* __restrict__ dh, const int* __restrict__ dr,
        const int* __restrict__ dt,
        const int* __restrict__ qh, const int* __restrict__ qr,
        const int* __restrict__ qt,
        uint32_t* __restrict__ bloom, uint32_t* __restrict__ flagbits,
        uint32_t* __restrict__ sent, uint32_t* __restrict__ keys,
        float* __restrict__ out,
        uint32_t tmask, int n8, int N, int Q, int zeroWords, int keyWords) {
    cg::grid_group grid = cg::this_grid();
    int gtid = blockIdx.x * blockDim.x + threadIdx.x;
    int gstride = gridDim.x * blockDim.x;

    // Phase A: init ws
    for (int i = gtid; i < zeroWords; i += gstride) bloom[i] = 0u;
    for (int i = gtid; i < keyWords;  i += gstride) keys[i] = EMPTY;
    grid.sync();

    // Phase B: insert query keys
    for (int i = gtid; i < Q; i += gstride) {
        uint32_t key = key32(qh[i], qr[i], qt[i]);
        if (key != EMPTY) {
            uint32_t w, m; bloom_wm(key, &w, &m);
            atomicOr(&bloom[w], m);
            uint32_t slot = hash2(key) & tmask;
            while (true) {
                uint32_t prev = atomicCAS(&keys[slot], EMPTY, key);
                if (prev == EMPTY || prev == key) break;
                slot = (slot + 1) & tmask;
            }
        }
    }
    grid.sync();

    // Phase C: LDS bloom + stream scan with 10-deep register deferred-probe queue
    __shared__ uint32_t lb[BWORDS];
    {
        const iv4* gb = (const iv4*)bloom;
        iv4* lb4 = (iv4*)lb;
        for (int i = threadIdx.x; i < BWORDS / 4; i += TPB) lb4[i] = gb[i];
    }
    __syncthreads();

    const iv4* H = (const iv4*)dh;
    const iv4* R = (const iv4*)dr;
    const iv4* T = (const iv4*)dt;
    int cnt = 0;
    uint32_t q0=0,q1=0,q2=0,q3=0,q4=0,q5=0,q6=0,q7=0,q8=0,q9=0;

#define TESTQ(kk, vv, mm)                                                          \
    if ((kk) == EMPTY) *sent = 1u;                                                 \
    else if (((vv) & (mm)) == (mm)) {                                              \
        if (cnt < 10) { q9=q8; q8=q7; q7=q6; q6=q5; q5=q4; q4=q3; q3=q2; q2=q1;    \
                        q1=q0; q0=(kk); cnt++; }                                   \
        else probe_mark((kk), keys, flagbits, tmask);                              \
    }
#define GRP4(h4, r4, t4)                                                           \
    {                                                                              \
        uint32_t k0 = key32((h4).x, (r4).x, (t4).x), k1 = key32((h4).y, (r4).y, (t4).y); \
        uint32_t k2 = key32((h4).z, (r4).z, (t4).z), k3 = key32((h4).w, (r4).w, (t4).w); \
        uint32_t w0,m0,w1,m1,w2,m2,w3,m3;                                          \
        bloom_wm(k0,&w0,&m0); bloom_wm(k1,&w1,&m1);                                \
        bloom_wm(k2,&w2,&m2); bloom_wm(k3,&w3,&m3);                                \
        uint32_t v0 = lb[w0], v1 = lb[w1], v2 = lb[w2], v3 = lb[w3];               \
        TESTQ(k0, v0, m0) TESTQ(k1, v1, m1) TESTQ(k2, v2, m2) TESTQ(k3, v3, m3)    \
    }

    for (int j = gtid; j < n8; j += gstride) {
        iv4 hA = __builtin_nontemporal_load(&H[j]);
        iv4 hB = __builtin_nontemporal_load(&H[j + n8]);
        iv4 rA = __builtin_nontemporal_load(&R[j]);
        iv4 rB = __builtin_nontemporal_load(&R[j + n8]);
        iv4 tA = __builtin_nontemporal_load(&T[j]);
        iv4 tB = __builtin_nontemporal_load(&T[j + n8]);
        GRP4(hA, rA, tA) GRP4(hB, rB, tB)
    }
#undef GRP4
#undef TESTQ

    int rem = N - 8 * n8;
    if (blockIdx.x == 0 && (int)threadIdx.x < rem) {
        int j = 8 * n8 + threadIdx.x;
        uint32_t k = key32(dh[j], dr[j], dt[j]);
        if (k == EMPTY) *sent = 1u;
        else probe_mark(k, keys, flagbits, tmask);
    }

    if (cnt > 0) probe_mark(q0, keys, flagbits, tmask);
    if (cnt > 1) probe_mark(q1, keys, flagbits, tmask);
    if (cnt > 2) probe_mark(q2, keys, flagbits, tmask);
    if (cnt > 3) probe_mark(q3, keys, flagbits, tmask);
    if (cnt > 4) probe_mark(q4, keys, flagbits, tmask);
    if (cnt > 5) probe_mark(q5, keys, flagbits, tmask);
    if (cnt > 6) probe_mark(q6, keys, flagbits, tmask);
    if (cnt > 7) probe_mark(q7, keys, flagbits, tmask);
    if (cnt > 8) probe_mark(q8, keys, flagbits, tmask);
    if (cnt > 9) probe_mark(q9, keys, flagbits, tmask);

    grid.sync();

    // Phase D: output
    for (int i = gtid; i < Q; i += gstride) {
        uint32_t key = key32(qh[i], qr[i], qt[i]);
        float v = -5.0f;
        if (key == EMPTY) {
            v = (*sent) ? 5.0f : -5.0f;
        } else {
            uint32_t slot = hash2(key) & tmask;
            while (true) {
                uint32_t kv = keys[slot];
                if (kv == key) { v = ((flagbits[slot >> 5] >> (slot & 31)) & 1u) ? 5.0f : -5.0f; break; }
                if (kv == EMPTY) break;
                slot = (slot + 1) & tmask;
            }
        }
        out[i] = v;
    }
}

// ================= Fallback kernels (byte-identical to r11) =================
__global__ void k_zero(uint32_t* __restrict__ p, int zeroWords, int totalWords) {
    int stride = gridDim.x * blockDim.x;
    for (int i = blockIdx.x * blockDim.x + threadIdx.x; i < totalWords; i += stride)
        p[i] = (i < zeroWords) ? 0u : EMPTY;
}

__global__ void k_insert(const int* __restrict__ qh, const int* __restrict__ qr,
                         const int* __restrict__ qt,
                         uint32_t* __restrict__ bloom, uint32_t* __restrict__ keys,
                         uint32_t tmask, int Q) {
    int i = blockIdx.x * blockDim.x + threadIdx.x;
    if (i >= Q) return;
    uint32_t key = key32(qh[i], qr[i], qt[i]);
    if (key == EMPTY) return;
    uint32_t w, m; bloom_wm(key, &w, &m);
    atomicOr(&bloom[w], m);
    uint32_t slot = hash2(key) & tmask;
    while (true) {
        uint32_t prev = atomicCAS(&keys[slot], EMPTY, key);
        if (prev == EMPTY || prev == key) return;
        slot = (slot + 1) & tmask;
    }
}

__global__ __launch_bounds__(TPB, 8) void k_scan(
        const int* __restrict__ dh, const int* __restrict__ dr,
        const int* __restrict__ dt,
        const uint32_t* __restrict__ bloom,
        const uint32_t* __restrict__ keys,
        uint32_t* __restrict__ flagbits, uint32_t* __restrict__ sent,
        uint32_t tmask, int n8, int N) {
    __shared__ uint32_t lb[BWORDS];
    {
        const iv4* gb = (const iv4*)bloom;
        iv4* lb4 = (iv4*)lb;
        for (int i = threadIdx.x; i < BWORDS / 4; i += TPB) lb4[i] = gb[i];
    }
    __syncthreads();

    const iv4* H = (const iv4*)dh;
    const iv4* R = (const iv4*)dr;
    const iv4* T = (const iv4*)dt;
    int cnt = 0;
    uint32_t q0 = 0, q1 = 0, q2 = 0, q3 = 0, q4 = 0, q5 = 0;
    int stride = gridDim.x * blockDim.x;

#define TESTQ(kk, vv, mm)                                                          \
    if ((kk) == EMPTY) *sent = 1u;                                                 \
    else if (((vv) & (mm)) == (mm)) {                                              \
        if (cnt < 6) { q5 = q4; q4 = q3; q3 = q2; q2 = q1; q1 = q0; q0 = (kk); cnt++; } \
        else probe_mark((kk), keys, flagbits, tmask);                              \
    }
#define GRP4(h4, r4, t4)                                                           \
    {                                                                              \
        uint32_t k0 = key32((h4).x, (r4).x, (t4).x), k1 = key32((h4).y, (r4).y, (t4).y); \
        uint32_t k2 = key32((h4).z, (r4).z, (t4).z), k3 = key32((h4).w, (r4).w, (t4).w); \
        uint32_t w0,m0,w1,m1,w2,m2,w3,m3;                                          \
        bloom_wm(k0,&w0,&m0); bloom_wm(k1,&w1,&m1);                                \
        bloom_wm(k2,&w2,&m2); bloom_wm(k3,&w3,&m3);                                \
        uint32_t v0 = lb[w0], v1 = lb[w1], v2 = lb[w2], v3 = lb[w3];               \
        TESTQ(k0, v0, m0) TESTQ(k1, v1, m1) TESTQ(k2, v2, m2) TESTQ(k3, v3, m3)    \
    }

    for (int j = blockIdx.x * blockDim.x + threadIdx.x; j < n8; j += stride) {
        iv4 hA = __builtin_nontemporal_load(&H[j]);
        iv4 hB = __builtin_nontemporal_load(&H[j + n8]);
        iv4 rA = __builtin_nontemporal_load(&R[j]);
        iv4 rB = __builtin_nontemporal_load(&R[j + n8]);
        iv4 tA = __builtin_nontemporal_load(&T[j]);
        iv4 tB = __builtin_nontemporal_load(&T[j + n8]);
        GRP4(hA, rA, tA) GRP4(hB, rB, tB)
    }
#undef GRP4
#undef TESTQ

    int rem = N - 8 * n8;
    if (blockIdx.x == 0 && (int)threadIdx.x < rem) {
        int j = 8 * n8 + threadIdx.x;
        uint32_t k = key32(dh[j], dr[j], dt[j]);
        if (k == EMPTY) *sent = 1u;
        else probe_mark(k, keys, flagbits, tmask);
    }

    if (cnt > 0) probe_mark(q0, keys, flagbits, tmask);
    if (cnt > 1) probe_mark(q1, keys, flagbits, tmask);
    if (cnt > 2) probe_mark(q2, keys, flagbits, tmask);
    if (cnt > 3) probe_mark(q3, keys, flagbits, tmask);
    if (cnt > 4) probe_mark(q4, keys, flagbits, tmask);
    if (cnt > 5) probe_mark(q5, keys, flagbits, tmask);
}

__global__ void k_out(const int* __restrict__ qh, const int* __restrict__ qr,
                      const int* __restrict__ qt,
                      const uint32_t* __restrict__ keys,
                      const uint32_t* __restrict__ flagbits,
                      const uint32_t* __restrict__ sent,
                      float* __restrict__ out, uint32_t tmask, int Q) {
    int i = blockIdx.x * blockDim.x + threadIdx.x;
    if (i >= Q) return;
    uint32_t key = key32(qh[i], qr[i], qt[i]);
    float v = -5.0f;
    if (key == EMPTY) {
        v = (*sent) ? 5.0f : -5.0f;
    } else {
        uint32_t slot = hash2(key) & tmask;
        while (true) {
            uint32_t kv = keys[slot];
            if (kv == key) { v = ((flagbits[slot >> 5] >> (slot & 31)) & 1u) ? 5.0f : -5.0f; break; }
            if (kv == EMPTY) break;
            slot = (slot + 1) & tmask;
        }
    }
    out[i] = v;
}

extern "C" void kernel_launch(void* const* d_in, const int* in_sizes, int n_in,
                              void* d_out, int out_size, void* d_ws, size_t ws_size,
                              hipStream_t stream) {
    const int* qh = (const int*)d_in[0];
    const int* qr = (const int*)d_in[1];
    const int* qt = (const int*)d_in[2];
    const int* data = (const int*)d_in[3];
    int Q = in_sizes[0];
    int N = in_sizes[3] / 3;
    const int* dh = data;
    const int* dr = data + (size_t)N;
    const int* dt = data + 2 * (size_t)N;
    float* out = (float*)d_out;

    int tb = 18;
    size_t bloomB = (size_t)BWORDS * 4;        // 64 KB
    size_t need = bloomB + ((size_t)1 << (tb - 3)) + 256 + ((size_t)4 << tb);
    if (need > ws_size) tb = 17;
    size_t flagB = (size_t)1 << (tb - 3);
    uint32_t tmask = ((uint32_t)1 << tb) - 1u;

    uint32_t* bloom    = (uint32_t*)d_ws;
    uint32_t* flagbits = (uint32_t*)((char*)d_ws + bloomB);
    uint32_t* sent     = (uint32_t*)((char*)d_ws + bloomB + flagB);
    uint32_t* keys     = (uint32_t*)((char*)d_ws + bloomB + flagB + 256);

    int zeroWords = (int)((bloomB + flagB + 256) / 4);
    int keyWords  = 1 << tb;
    int n8 = N / 8;

    // Occupancy-gated cooperative launch; stateless decision, same every call.
    int occ = 0;
    hipError_t oe = hipOccupancyMaxActiveBlocksPerMultiprocessor(
        &occ, (const void*)k_fused, TPB, 0);
    bool launched = false;
    if (oe == hipSuccess && occ >= 1) {
        int nblk = (occ >= 2) ? 512 : 256;
        void* args[] = { (void*)&dh, (void*)&dr, (void*)&dt,
                         (void*)&qh, (void*)&qr, (void*)&qt,
                         (void*)&bloom, (void*)&flagbits, (void*)&sent, (void*)&keys,
                         (void*)&out,
                         (void*)&tmask, (void*)&n8, (void*)&N, (void*)&Q,
                         (void*)&zeroWords, (void*)&keyWords };
        hipError_t le = hipLaunchCooperativeKernel((const void*)k_fused,
                                                   dim3(nblk), dim3(TPB),
                                                   args, 0, stream);
        launched = (le == hipSuccess);
    }

    if (!launched) {   // r11 fallback path (proven 209 us)
        int zw = zeroWords, totalWords = zw + keyWords;
        k_zero<<<1024, 256, 0, stream>>>((uint32_t*)d_ws, zw, totalWords);
        int qblocks = (Q + 255) / 256;
        k_insert<<<qblocks, 256, 0, stream>>>(qh, qr, qt, bloom, keys, tmask, Q);
        k_scan<<<512, TPB, 0, stream>>>(dh, dr, dt, bloom, keys, flagbits,
                                        sent, tmask, n8, N);
        k_out<<<qblocks, 256, 0, stream>>>(qh, qr, qt, keys, flagbits, sent, out, tmask, Q);
    }
}

// Round 15
// 216.632 us; speedup vs baseline: 1.3434x; 1.3434x over previous
//
#include <hip/hip_runtime.h>
#include <stdint.h>

// PerfeCT membership: out[i] = +5.0 if (h,r,t) appears in data, else -5.0.
// key32 = ((h*15000+r)*15000+t) mod 2^32 (replicates reference's int32 overflow).
// r14 post-mortem: coop fusion ran but grid.sync() cost ~95us on 8 non-coherent
// XCDs (k_fused 196us vs ~100us of work) -> REVERTED to r11 4-kernel path.
// r15 scan experiment (single theory, two symptoms): plain loads (NT may defeat
// L3-hit servicing; FETCH was ~67MB = half stream from HBM) + BLOCK-CONTIGUOUS
// tiling (grid-stride jumped 8MB/iter across 6 streams 40MB apart, killing
// L2-sector/DRAM-row locality; copies that hit 6.3TB/s read contiguously).

typedef int iv4 __attribute__((ext_vector_type(4)));

#define EMPTY  0xFFFFFFFFu
#define BWORDS 16384     // 2^19-bit bloom = 64 KB LDS -> 2 blocks/CU = 32 waves/CU
#define TPB    1024
#define NBLK   512

static __device__ __forceinline__ uint32_t mix32(uint32_t x) {
    x ^= x >> 16; x *= 0x85ebca6bu;
    x ^= x >> 13; x *= 0xc2b2ae35u;
    x ^= x >> 16;
    return x;
}
static __device__ __forceinline__ uint32_t hash2(uint32_t x) {
    return mix32(x ^ 0x9E3779B9u);
}
static __device__ __forceinline__ uint32_t key32(int h, int r, int t) {
    return ((uint32_t)h * 15000u + (uint32_t)r) * 15000u + (uint32_t)t;
}
static __device__ __forceinline__ void bloom_wm(uint32_t key, uint32_t* w, uint32_t* m) {
    uint32_t z = mix32(key);
    *w = z & (BWORDS - 1u);
    *m = (1u << ((z >> 14) & 31u)) | (1u << ((z >> 19) & 31u));
}

static __device__ __forceinline__ void probe_mark(uint32_t key,
                                                  const uint32_t* __restrict__ keys,
                                                  uint32_t* __restrict__ flagbits,
                                                  uint32_t tmask) {
    uint32_t slot = hash2(key) & tmask;
    while (true) {
        uint32_t v = keys[slot];
        if (v == key) { atomicOr(&flagbits[slot >> 5], 1u << (slot & 31)); return; }
        if (v == EMPTY) return;
        slot = (slot + 1) & tmask;
    }
}

// ws: [bloom 64KB][flagbits (1<<tb)/8][hdr 256B: sent@0][keys 4<<tb]
__global__ void k_zero(uint32_t* __restrict__ p, int zeroWords, int totalWords) {
    int stride = gridDim.x * blockDim.x;
    for (int i = blockIdx.x * blockDim.x + threadIdx.x; i < totalWords; i += stride)
        p[i] = (i < zeroWords) ? 0u : EMPTY;
}

__global__ void k_insert(const int* __restrict__ qh, const int* __restrict__ qr,
                         const int* __restrict__ qt,
                         uint32_t* __restrict__ bloom, uint32_t* __restrict__ keys,
                         uint32_t tmask, int Q) {
    int i = blockIdx.x * blockDim.x + threadIdx.x;
    if (i >= Q) return;
    uint32_t key = key32(qh[i], qr[i], qt[i]);
    if (key == EMPTY) return;      // sentinel-valued query: k_out consults `sent`
    uint32_t w, m; bloom_wm(key, &w, &m);
    atomicOr(&bloom[w], m);
    uint32_t slot = hash2(key) & tmask;
    while (true) {
        uint32_t prev = atomicCAS(&keys[slot], EMPTY, key);
        if (prev == EMPTY || prev == key) return;
        slot = (slot + 1) & tmask;
    }
}

// Block-contiguous scan: block b owns int4 range [qs,qe) of each column
// (~78KB/column window), split into two in-window streams (MLP 6, coalesced).
__global__ __launch_bounds__(TPB, 8) void k_scan(
        const int* __restrict__ dh, const int* __restrict__ dr,
        const int* __restrict__ dt,
        const uint32_t* __restrict__ bloom,
        const uint32_t* __restrict__ keys,
        uint32_t* __restrict__ flagbits, uint32_t* __restrict__ sent,
        uint32_t tmask, int c4, int tot4, int N) {
    __shared__ uint32_t lb[BWORDS];
    {
        const iv4* gb = (const iv4*)bloom;
        iv4* lb4 = (iv4*)lb;
        for (int i = threadIdx.x; i < BWORDS / 4; i += TPB) lb4[i] = gb[i];
    }
    __syncthreads();

    const iv4* H = (const iv4*)dh;
    const iv4* R = (const iv4*)dr;
    const iv4* T = (const iv4*)dt;
    int cnt = 0;
    uint32_t q0 = 0, q1 = 0, q2 = 0, q3 = 0, q4 = 0, q5 = 0;

#define TESTQ(kk, vv, mm)                                                          \
    if ((kk) == EMPTY) *sent = 1u;                                                 \
    else if (((vv) & (mm)) == (mm)) {                                              \
        if (cnt < 6) { q5 = q4; q4 = q3; q3 = q2; q2 = q1; q1 = q0; q0 = (kk); cnt++; } \
        else probe_mark((kk), keys, flagbits, tmask);                              \
    }
#define GRP4(h4, r4, t4)                                                           \
    {                                                                              \
        uint32_t k0 = key32((h4).x, (r4).x, (t4).x), k1 = key32((h4).y, (r4).y, (t4).y); \
        uint32_t k2 = key32((h4).z, (r4).z, (t4).z), k3 = key32((h4).w, (r4).w, (t4).w); \
        uint32_t w0,m0,w1,m1,w2,m2,w3,m3;                                          \
        bloom_wm(k0,&w0,&m0); bloom_wm(k1,&w1,&m1);                                \
        bloom_wm(k2,&w2,&m2); bloom_wm(k3,&w3,&m3);                                \
        uint32_t v0 = lb[w0], v1 = lb[w1], v2 = lb[w2], v3 = lb[w3];               \
        TESTQ(k0, v0, m0) TESTQ(k1, v1, m1) TESTQ(k2, v2, m2) TESTQ(k3, v3, m3)    \
    }

    int qs = blockIdx.x * c4;
    int qe = qs + c4; if (qe > tot4) qe = tot4;
    if (qs < qe) {
        int S = qe - qs;
        int pairs = S >> 1;
        for (int i = threadIdx.x; i < pairs; i += TPB) {
            int a = qs + i;
            int b = qs + pairs + i;
            iv4 hA = H[a], hB = H[b];
            iv4 rA = R[a], rB = R[b];
            iv4 tA = T[a], tB = T[b];
            GRP4(hA, rA, tA) GRP4(hB, rB, tB)
        }
        if ((S & 1) && threadIdx.x == 0) {    // odd int4 leftover in this block's range
            int a = qe - 1;
            iv4 hA = H[a], rA = R[a], tA = T[a];
            GRP4(hA, rA, tA)
        }
    }
#undef GRP4
#undef TESTQ

    // global remainder [4*tot4, N) — 0 for N=10M
    int rem = N - 4 * tot4;
    if (blockIdx.x == 0 && (int)threadIdx.x < rem) {
        int j = 4 * tot4 + threadIdx.x;
        uint32_t k = key32(dh[j], dr[j], dt[j]);
        if (k == EMPTY) *sent = 1u;
        else probe_mark(k, keys, flagbits, tmask);
    }

    // drain register queue (all waves concurrently -> latency hidden by TLP)
    if (cnt > 0) probe_mark(q0, keys, flagbits, tmask);
    if (cnt > 1) probe_mark(q1, keys, flagbits, tmask);
    if (cnt > 2) probe_mark(q2, keys, flagbits, tmask);
    if (cnt > 3) probe_mark(q3, keys, flagbits, tmask);
    if (cnt > 4) probe_mark(q4, keys, flagbits, tmask);
    if (cnt > 5) probe_mark(q5, keys, flagbits, tmask);
}

__global__ void k_out(const int* __restrict__ qh, const int* __restrict__ qr,
                      const int* __restrict__ qt,
                      const uint32_t* __restrict__ keys,
                      const uint32_t* __restrict__ flagbits,
                      const uint32_t* __restrict__ sent,
                      float* __restrict__ out, uint32_t tmask, int Q) {
    int i = blockIdx.x * blockDim.x + threadIdx.x;
    if (i >= Q) return;
    uint32_t key = key32(qh[i], qr[i], qt[i]);
    float v = -5.0f;
    if (key == EMPTY) {
        v = (*sent) ? 5.0f : -5.0f;
    } else {
        uint32_t slot = hash2(key) & tmask;
        while (true) {
            uint32_t kv = keys[slot];
            if (kv == key) { v = ((flagbits[slot >> 5] >> (slot & 31)) & 1u) ? 5.0f : -5.0f; break; }
            if (kv == EMPTY) break;
            slot = (slot + 1) & tmask;
        }
    }
    out[i] = v;
}

extern "C" void kernel_launch(void* const* d_in, const int* in_sizes, int n_in,
                              void* d_out, int out_size, void* d_ws, size_t ws_size,
                              hipStream_t stream) {
    const int* qh = (const int*)d_in[0];
    const int* qr = (const int*)d_in[1];
    const int* qt = (const int*)d_in[2];
    const int* data = (const int*)d_in[3];
    int Q = in_sizes[0];
    int N = in_sizes[3] / 3;
    const int* dh = data;
    const int* dr = data + (size_t)N;
    const int* dt = data + 2 * (size_t)N;
    float* out = (float*)d_out;

    int tb = 18;                               // 100K keys, alpha 0.38; floor 17 (livelock guard)
    size_t bloomB = (size_t)BWORDS * 4;        // 64 KB
    size_t need = bloomB + ((size_t)1 << (tb - 3)) + 256 + ((size_t)4 << tb);
    if (need > ws_size) tb = 17;
    size_t flagB = (size_t)1 << (tb - 3);
    uint32_t tmask = ((uint32_t)1 << tb) - 1u;

    uint32_t* bloom    = (uint32_t*)d_ws;
    uint32_t* flagbits = (uint32_t*)((char*)d_ws + bloomB);
    uint32_t* sent     = (uint32_t*)((char*)d_ws + bloomB + flagB);
    uint32_t* keys     = (uint32_t*)((char*)d_ws + bloomB + flagB + 256);

    int zeroWords  = (int)((bloomB + flagB + 256) / 4);
    int totalWords = zeroWords + (1 << tb);
    k_zero<<<1024, 256, 0, stream>>>((uint32_t*)d_ws, zeroWords, totalWords);

    int qblocks = (Q + 255) / 256;
    k_insert<<<qblocks, 256, 0, stream>>>(qh, qr, qt, bloom, keys, tmask, Q);

    int tot4 = N / 4;
    int c4 = (tot4 + NBLK - 1) / NBLK;
    c4 = (c4 + 1) & ~1;                        // even chunk so the pair-split is clean
    k_scan<<<NBLK, TPB, 0, stream>>>(dh, dr, dt, bloom, keys, flagbits,
                                     sent, tmask, c4, tot4, N);

    k_out<<<qblocks, 256, 0, stream>>>(qh, qr, qt, keys, flagbits, sent, out, tmask, Q);
}